// Round 4
// baseline (335.185 us; speedup 1.0000x reference)
//
#include <hip/hip_runtime.h>
#include <math.h>

#define B_ 8
#define T_ 4096
#define D_ 192
#define E_ 6
#define H_ 768            // 4*D
#define NTOK (B_*T_)      // 32768
#define TT 8              // tokens per block (24 accumulators/thread -> fits 64-VGPR budget)
#define NT 3              // number of expert types

// ws float-offset layout
#define WS_TPART 0                  // 3*768 (rb1 folded in)
#define WS_W2M   (NT*H_)            // 768
#define WS_TEMP  (WS_W2M + H_)      // 1
#define WS_RB2M  (WS_TEMP + 1)      // 1
#define WS_ENT   (WS_RB2M + 1)      // 1 (float accumulator, zeroed each call)
#define WS_LOAD  (WS_ENT + 1)       // 6 uints (zeroed each call)

// Fast erf (Abramowitz-Stegun 7.1.26): |err| <= 1.5e-7, single path, ~14 VALU.
// logits error contribution ~3e-8 -> no top-k flips vs numpy erf reference.
__device__ __forceinline__ float gelu_f(float v) {
    float x  = v * 0.70710678118654752440f;
    float ax = fabsf(x);
    float t  = __builtin_amdgcn_rcpf(fmaf(0.3275911f, ax, 1.0f));   // v_rcp_f32
    float y  = t * fmaf(t, fmaf(t, fmaf(t, fmaf(t, 1.061405429f, -1.453152027f),
                                         1.421413741f), -0.284496736f), 0.254829592f);
    float em = __expf(-ax * ax);                                    // v_exp_f32 path
    float er = fmaf(-y, em, 1.0f);                                  // erf(|x|)
    er = copysignf(er, x);
    return 0.5f * v * (1.0f + er);
}
__device__ __forceinline__ float softplus_f(float x) {
    // jax.nn.softplus = max(x,0) + log1p(exp(-|x|))  (exactness matters less here;
    // keep libm since it's only E_ per token)
    return fmaxf(x, 0.0f) + log1pf(expf(-fabsf(x)));
}

__global__ __launch_bounds__(256) void prep_kernel(
    const float* __restrict__ type_emb,    // (3, 384)
    const float* __restrict__ rw1,         // (576, 768)
    const float* __restrict__ rb1,         // (768)
    const float* __restrict__ rw2,         // (768, 6)
    const float* __restrict__ rb2,         // (6)
    const float* __restrict__ temperature, // (1)
    float* __restrict__ wsF)
{
    int blk = blockIdx.x, tid = threadIdx.x;
    if (blk < 9) {
        // tpart[c][j] = sum_k type_emb[c][k] * rw1[192+k][j] + rb1[j]
        int o = blk * 256 + tid;          // 0..2303
        int c = o / H_, j = o % H_;
        float s = rb1[j];
        const float* te = type_emb + c * (2 * D_);
        #pragma unroll 4
        for (int k = 0; k < 2 * D_; ++k)
            s = fmaf(te[k], rw1[(size_t)(D_ + k) * H_ + j], s);
        wsF[WS_TPART + o] = s;
    } else {
        for (int j = tid; j < H_; j += 256) {
            float s = 0.f;
            #pragma unroll
            for (int e = 0; e < E_; ++e) s += rw2[(size_t)j * E_ + e];
            wsF[WS_W2M + j] = s * (1.0f / 6.0f);
        }
        if (tid == 0) {
            float decay = (float)pow(0.95, (double)(T_ / 100));   // 0.95^40
            float tv = temperature[0] * decay;
            tv = fminf(fmaxf(tv, 0.05f), 3.0f);
            wsF[WS_TEMP] = tv;
            float rs = 0.f;
            #pragma unroll
            for (int e = 0; e < E_; ++e) rs += rb2[e];
            wsF[WS_RB2M] = rs * (1.0f / 6.0f);
            wsF[WS_ENT] = 0.f;
            unsigned* lu = (unsigned*)(wsF + WS_LOAD);
            #pragma unroll
            for (int e = 0; e < E_; ++e) lu[e] = 0u;
        }
    }
}

// (256,8): 8 waves/EU -> total VGPR+AGPR cap 64. TT=8 keeps the live set ~40.
// (R2 lesson: 48 accumulators under a 64 cap spilled; 24 fit.)
__global__ __launch_bounds__(256, 8) void router_main(
    const float* __restrict__ x,            // (32768, 192)
    const float* __restrict__ noise,        // (32768, 6)
    const int*   __restrict__ expert_types, // (6)
    const float* __restrict__ nw1,          // (192, 12)
    const float* __restrict__ nb1,          // (12)
    const float* __restrict__ nw2,          // (12, 6)
    const float* __restrict__ nb2,          // (6)
    const float* __restrict__ rw1,          // wx = rows [0,192)
    float* __restrict__ wsF,
    float* __restrict__ out)                // p | idx(float) | aux
{
    __shared__ float xsT[D_][TT];       // 6 KB transposed x tile; rows 32B -> float4-aligned
    __shared__ float red[NT * TT][4];   // per-wave partials
    __shared__ float logits[TT][NT];
    __shared__ float h1[TT][12];
    __shared__ float noisy[TT][E_];
    __shared__ float ps[TT][2];
    __shared__ int   is_[TT][2];
    __shared__ float entArr[TT];
    __shared__ unsigned loadLds[E_];

    int tid = threadIdx.x;
    int tok0 = blockIdx.x * TT;
    int wave = tid >> 6, lane = tid & 63;

    // ---- stage x tile (coalesced global read, transposed LDS write)
    for (int i = tid; i < TT * D_; i += 256) {
        int t = i / D_, k = i % D_;
        xsT[k][t] = x[(size_t)tok0 * D_ + i];
    }
    if (tid < E_) loadLds[tid] = 0u;
    __syncthreads();

    // ---- phase 1: xp(8x768) = xtile(8x192) @ wx(192x768), held in registers
    // thread tid owns cols {tid, tid+256, tid+512} x 8 tokens (24 accumulators)
    float a0[TT], a1[TT], a2[TT];
    #pragma unroll
    for (int t = 0; t < TT; ++t) { a0[t] = 0.f; a1[t] = 0.f; a2[t] = 0.f; }
    #pragma unroll 2
    for (int k = 0; k < D_; ++k) {
        float w0 = rw1[(size_t)k * H_ + tid];
        float w1 = rw1[(size_t)k * H_ + tid + 256];
        float w2 = rw1[(size_t)k * H_ + tid + 512];
        const float4* xr = reinterpret_cast<const float4*>(&xsT[k][0]);
        float4 xv0 = xr[0], xv1 = xr[1];       // broadcast ds_read_b128 x2
        const float xv[TT] = { xv0.x, xv0.y, xv0.z, xv0.w,
                               xv1.x, xv1.y, xv1.z, xv1.w };
        #pragma unroll
        for (int t = 0; t < TT; ++t) {
            a0[t] = fmaf(xv[t], w0, a0[t]);
            a1[t] = fmaf(xv[t], w1, a1[t]);
            a2[t] = fmaf(xv[t], w2, a2[t]);
        }
    }

    // ---- phase 2 (fused): logits[t][c] = sum_j gelu(xp+tp)*w2m + rb2m
    // tp/w2m read from global AFTER the GEMM so they don't occupy registers
    // during phase 1 (L2-resident, coalesced across threads).
    float w2r0 = wsF[WS_W2M + tid];
    float w2r1 = wsF[WS_W2M + tid + 256];
    float w2r2 = wsF[WS_W2M + tid + 512];
    #pragma unroll
    for (int c = 0; c < NT; ++c) {
        float tp0 = wsF[WS_TPART + c * H_ + tid];
        float tp1 = wsF[WS_TPART + c * H_ + tid + 256];
        float tp2 = wsF[WS_TPART + c * H_ + tid + 512];
        #pragma unroll
        for (int t = 0; t < TT; ++t) {
            float g = gelu_f(a0[t] + tp0) * w2r0
                    + gelu_f(a1[t] + tp1) * w2r1
                    + gelu_f(a2[t] + tp2) * w2r2;
            #pragma unroll
            for (int off = 32; off; off >>= 1) g += __shfl_xor(g, off, 64);
            if (lane == 0) red[c * TT + t][wave] = g;
        }
    }
    __syncthreads();
    float rb2m = wsF[WS_RB2M];
    if (tid < NT * TT) {
        int c = tid / TT, t = tid % TT;
        logits[t][c] = red[tid][0] + red[tid][1] + red[tid][2] + red[tid][3] + rb2m;
    }
    __syncthreads();

    // ---- phase 3: noise MLP, noisy logits, top-2, softmax, entropy
    int t = tid >> 4, j = tid & 15;       // 16 threads per token, tokens 0..7 active
    if (t < TT && j < 12) {
        float s = nb1[j];
        for (int k = 0; k < D_; ++k) s = fmaf(xsT[k][t], nw1[k * 12 + j], s);
        h1[t][j] = gelu_f(s);
    }
    __syncthreads();
    float temp = wsF[WS_TEMP];
    if (t < TT && j < E_) {
        float s = nb2[j];
        #pragma unroll
        for (int i = 0; i < 12; ++i) s = fmaf(h1[t][i], nw2[i * E_ + j], s);
        float nsc = softplus_f(softplus_f(s));
        int ety = expert_types[j];
        float nv = logits[t][ety] + ((ety == 1) ? 0.3f : 0.0f)
                 + temp * (noise[(size_t)(tok0 + t) * E_ + j] * nsc);
        noisy[t][j] = nv;
    }
    __syncthreads();
    if (t < TT && j == 0) {
        // top-2, ties -> lower index first (strict > keeps earliest)
        float v1 = -1e30f; int i1 = 0;
        #pragma unroll
        for (int e = 0; e < E_; ++e) {
            float v = noisy[t][e];
            if (v > v1) { v1 = v; i1 = e; }
        }
        float v2 = -1e30f; int i2 = 0;
        #pragma unroll
        for (int e = 0; e < E_; ++e) {
            if (e == i1) continue;
            float v = noisy[t][e];
            if (v > v2) { v2 = v; i2 = e; }
        }
        float e2 = expf(v2 - v1);
        float denom = 1.0f + e2;
        float p1 = 1.0f / denom;
        float p2 = e2 / denom;
        ps[t][0] = p1; ps[t][1] = p2;
        is_[t][0] = i1; is_[t][1] = i2;
        entArr[t] = -(p1 * logf(p1 + 1e-8f) + p2 * logf(p2 + 1e-8f));
        atomicAdd(&loadLds[i1], 1u);
        atomicAdd(&loadLds[i2], 1u);
    }
    __syncthreads();

    // ---- outputs
    if (tid < TT * E_) {
        int tt = tid / E_, e = tid % E_;
        float v = 0.f;
        if (e == is_[tt][0])      v = ps[tt][0];
        else if (e == is_[tt][1]) v = ps[tt][1];
        out[(size_t)tok0 * E_ + tid] = v;
    }
    if (tid < TT * 2) {
        int tt = tid >> 1, s = tid & 1;
        out[(size_t)NTOK * E_ + (size_t)(tok0 + tt) * 2 + s] = (float)is_[tt][s];
    }
    if (tid == 0) {
        float es = 0.f;
        #pragma unroll
        for (int tt = 0; tt < TT; ++tt) es += entArr[tt];
        atomicAdd(&wsF[WS_ENT], es);
        unsigned* lu = (unsigned*)(wsF + WS_LOAD);
        #pragma unroll
        for (int e = 0; e < E_; ++e)
            if (loadLds[e]) atomicAdd(&lu[e], loadLds[e]);
    }
}

__global__ void finalize_kernel(const float* __restrict__ wsF,
                                float* __restrict__ out)
{
    if (threadIdx.x == 0 && blockIdx.x == 0) {
        const unsigned* lu = (const unsigned*)(wsF + WS_LOAD);
        double m = 0.0, l[E_];
        #pragma unroll
        for (int e = 0; e < E_; ++e) { l[e] = (double)lu[e]; m += l[e]; }
        m /= (double)E_;
        double var = 0.0;
        #pragma unroll
        for (int e = 0; e < E_; ++e) { double d = l[e] - m; var += d * d; }
        var /= (double)(E_ - 1);
        double stdl = sqrt(var);
        // importance = em.sum(0).mean(1) == 8*2/6 for every t -> std == 0 exactly
        double ent = (double)wsF[WS_ENT] / (double)NTOK;
        out[(size_t)NTOK * E_ + (size_t)NTOK * 2] = (float)(0.1 * ent + 0.2 * stdl);
    }
}

extern "C" void kernel_launch(void* const* d_in, const int* in_sizes, int n_in,
                              void* d_out, int out_size, void* d_ws, size_t ws_size,
                              hipStream_t stream)
{
    const float* x            = (const float*)d_in[0];
    const float* noise        = (const float*)d_in[1];
    const int*   expert_types = (const int*)  d_in[2];
    const float* type_emb     = (const float*)d_in[3];
    const float* nw1          = (const float*)d_in[4];
    const float* nb1          = (const float*)d_in[5];
    const float* nw2          = (const float*)d_in[6];
    const float* nb2          = (const float*)d_in[7];
    const float* rw1          = (const float*)d_in[8];
    const float* rb1          = (const float*)d_in[9];
    const float* rw2          = (const float*)d_in[10];
    const float* rb2          = (const float*)d_in[11];
    const float* temperature  = (const float*)d_in[12];
    float* out = (float*)d_out;
    float* wsF = (float*)d_ws;

    prep_kernel<<<10, 256, 0, stream>>>(type_emb, rw1, rb1, rw2, rb2, temperature, wsF);
    router_main<<<NTOK / TT, 256, 0, stream>>>(x, noise, expert_types,
                                               nw1, nb1, nw2, nb2, rw1, wsF, out);
    finalize_kernel<<<1, 64, 0, stream>>>(wsF, out);
}

// Round 5
// 298.780 us; speedup vs baseline: 1.1218x; 1.1218x over previous
//
#include <hip/hip_runtime.h>
#include <math.h>

#define B_ 8
#define T_ 4096
#define D_ 192
#define E_ 6
#define H_ 768            // 4*D
#define NTOK (B_*T_)      // 32768
#define TT 16             // tokens per block
#define NT 3              // number of expert types

// ws float-offset layout
#define WS_TPART 0                  // 3*768 (rb1 folded in)
#define WS_W2M   (NT*H_)            // 768
#define WS_TEMP  (WS_W2M + H_)      // 1
#define WS_RB2M  (WS_TEMP + 1)      // 1
#define WS_ENT   (WS_RB2M + 1)      // 1 (float accumulator, zeroed each call)
#define WS_LOAD  (WS_ENT + 1)       // 6 uints (zeroed each call)

// Fast erf (Abramowitz-Stegun 7.1.26): |err| <= 1.5e-7, single path.
__device__ __forceinline__ float gelu_f(float v) {
    float x  = v * 0.70710678118654752440f;
    float ax = fabsf(x);
    float t  = __builtin_amdgcn_rcpf(fmaf(0.3275911f, ax, 1.0f));   // v_rcp_f32
    float y  = t * fmaf(t, fmaf(t, fmaf(t, fmaf(t, 1.061405429f, -1.453152027f),
                                         1.421413741f), -0.284496736f), 0.254829592f);
    float em = __expf(-ax * ax);                                    // v_exp_f32 path
    float er = fmaf(-y, em, 1.0f);                                  // erf(|x|)
    er = copysignf(er, x);
    return 0.5f * v * (1.0f + er);
}
__device__ __forceinline__ float softplus_f(float x) {
    return fmaxf(x, 0.0f) + log1pf(expf(-fabsf(x)));
}

__global__ __launch_bounds__(256) void prep_kernel(
    const float* __restrict__ type_emb,    // (3, 384)
    const float* __restrict__ rw1,         // (576, 768)
    const float* __restrict__ rb1,         // (768)
    const float* __restrict__ rw2,         // (768, 6)
    const float* __restrict__ rb2,         // (6)
    const float* __restrict__ temperature, // (1)
    float* __restrict__ wsF)
{
    int blk = blockIdx.x, tid = threadIdx.x;
    if (blk < 9) {
        int o = blk * 256 + tid;          // 0..2303
        int c = o / H_, j = o % H_;
        float s = rb1[j];
        const float* te = type_emb + c * (2 * D_);
        #pragma unroll 4
        for (int k = 0; k < 2 * D_; ++k)
            s = fmaf(te[k], rw1[(size_t)(D_ + k) * H_ + j], s);
        wsF[WS_TPART + o] = s;
    } else {
        for (int j = tid; j < H_; j += 256) {
            float s = 0.f;
            #pragma unroll
            for (int e = 0; e < E_; ++e) s += rw2[(size_t)j * E_ + e];
            wsF[WS_W2M + j] = s * (1.0f / 6.0f);
        }
        if (tid == 0) {
            float decay = (float)pow(0.95, (double)(T_ / 100));   // 0.95^40
            float tv = temperature[0] * decay;
            tv = fminf(fmaxf(tv, 0.05f), 3.0f);
            wsF[WS_TEMP] = tv;
            float rs = 0.f;
            #pragma unroll
            for (int e = 0; e < E_; ++e) rs += rb2[e];
            wsF[WS_RB2M] = rs * (1.0f / 6.0f);
            wsF[WS_ENT] = 0.f;
            unsigned* lu = (unsigned*)(wsF + WS_LOAD);
            #pragma unroll
            for (int e = 0; e < E_; ++e) lu[e] = 0u;
        }
    }
}

// R5 structure: x values are block-uniform -> scalar (s_load) operands; phase 1
// is pure v_fma with one SGPR source. No x LDS staging at all. TT=16 amortizes
// the 3 weight loads/k over 16 tokens. (256,4): 48 accs + temps fit 128-reg cap
// (R2 lesson: never force a cap below the live set).
__global__ __launch_bounds__(256, 4) void router_main(
    const float* __restrict__ x,            // (32768, 192)
    const float* __restrict__ noise,        // (32768, 6)
    const int*   __restrict__ expert_types, // (6)
    const float* __restrict__ nw1,          // (192, 12)
    const float* __restrict__ nb1,          // (12)
    const float* __restrict__ nw2,          // (12, 6)
    const float* __restrict__ nb2,          // (6)
    const float* __restrict__ rw1,          // wx = rows [0,192)
    float* __restrict__ wsF,
    float* __restrict__ out)                // p | idx(float) | aux
{
    __shared__ float red[NT * TT][4];   // per-wave partials
    __shared__ float logits[TT][NT];
    __shared__ float h1[TT][12];
    __shared__ float noisy[TT][E_];
    __shared__ float ps[TT][2];
    __shared__ int   is_[TT][2];
    __shared__ float entArr[TT];
    __shared__ unsigned loadLds[E_];

    int tid = threadIdx.x;
    int tok0 = blockIdx.x * TT;
    int wave = tid >> 6, lane = tid & 63;

    if (tid < E_) loadLds[tid] = 0u;

    // ---- phase 1: xp(16x768) = xtile(16x192) @ wx(192x768), accs in registers.
    // x loads are uniform (blockIdx + loop constants only) -> scalar loads.
    const float* __restrict__ xrow = x + (size_t)tok0 * D_;
    const float* __restrict__ wcol = rw1 + tid;

    float a0[TT], a1[TT], a2[TT];
    #pragma unroll
    for (int t = 0; t < TT; ++t) { a0[t] = 0.f; a1[t] = 0.f; a2[t] = 0.f; }

    #pragma unroll 2
    for (int k = 0; k < D_; ++k) {
        float w0 = wcol[(size_t)k * H_];
        float w1 = wcol[(size_t)k * H_ + 256];
        float w2 = wcol[(size_t)k * H_ + 512];
        #pragma unroll
        for (int t = 0; t < TT; ++t) {
            float xv = xrow[t * D_ + k];          // uniform -> SGPR
            a0[t] = fmaf(xv, w0, a0[t]);
            a1[t] = fmaf(xv, w1, a1[t]);
            a2[t] = fmaf(xv, w2, a2[t]);
        }
    }

    // ---- phase 2 (fused): logits[t][c] = sum_j gelu(xp+tp)*w2m + rb2m
    float w2r0 = wsF[WS_W2M + tid];
    float w2r1 = wsF[WS_W2M + tid + 256];
    float w2r2 = wsF[WS_W2M + tid + 512];
    #pragma unroll
    for (int c = 0; c < NT; ++c) {
        float tp0 = wsF[WS_TPART + c * H_ + tid];
        float tp1 = wsF[WS_TPART + c * H_ + tid + 256];
        float tp2 = wsF[WS_TPART + c * H_ + tid + 512];
        #pragma unroll
        for (int t = 0; t < TT; ++t) {
            float g = gelu_f(a0[t] + tp0) * w2r0
                    + gelu_f(a1[t] + tp1) * w2r1
                    + gelu_f(a2[t] + tp2) * w2r2;
            #pragma unroll
            for (int off = 32; off; off >>= 1) g += __shfl_xor(g, off, 64);
            if (lane == 0) red[c * TT + t][wave] = g;
        }
    }
    __syncthreads();
    float rb2m = wsF[WS_RB2M];
    if (tid < NT * TT) {
        int c = tid / TT, t = tid % TT;
        logits[t][c] = red[tid][0] + red[tid][1] + red[tid][2] + red[tid][3] + rb2m;
    }
    __syncthreads();

    // ---- phase 3: noise MLP, noisy logits, top-2, softmax, entropy
    int t = tid >> 4, j = tid & 15;       // 16 threads per token
    if (j < 12) {
        const float* xr = x + (size_t)(tok0 + t) * D_;
        float s = nb1[j];
        #pragma unroll 4
        for (int k = 0; k < D_; ++k) s = fmaf(xr[k], nw1[k * 12 + j], s);
        h1[t][j] = gelu_f(s);
    }
    __syncthreads();
    float temp = wsF[WS_TEMP];
    if (j < E_) {
        float s = nb2[j];
        #pragma unroll
        for (int i = 0; i < 12; ++i) s = fmaf(h1[t][i], nw2[i * E_ + j], s);
        float nsc = softplus_f(softplus_f(s));
        int ety = expert_types[j];
        float nv = logits[t][ety] + ((ety == 1) ? 0.3f : 0.0f)
                 + temp * (noise[(size_t)(tok0 + t) * E_ + j] * nsc);
        noisy[t][j] = nv;
    }
    __syncthreads();
    if (j == 0) {
        // top-2, ties -> lower index first (strict > keeps earliest)
        float v1 = -1e30f; int i1 = 0;
        #pragma unroll
        for (int e = 0; e < E_; ++e) {
            float v = noisy[t][e];
            if (v > v1) { v1 = v; i1 = e; }
        }
        float v2 = -1e30f; int i2 = 0;
        #pragma unroll
        for (int e = 0; e < E_; ++e) {
            if (e == i1) continue;
            float v = noisy[t][e];
            if (v > v2) { v2 = v; i2 = e; }
        }
        float e2 = expf(v2 - v1);
        float denom = 1.0f + e2;
        float p1 = 1.0f / denom;
        float p2 = e2 / denom;
        ps[t][0] = p1; ps[t][1] = p2;
        is_[t][0] = i1; is_[t][1] = i2;
        entArr[t] = -(p1 * logf(p1 + 1e-8f) + p2 * logf(p2 + 1e-8f));
        atomicAdd(&loadLds[i1], 1u);
        atomicAdd(&loadLds[i2], 1u);
    }
    __syncthreads();

    // ---- outputs
    for (int i = tid; i < TT * E_; i += 256) {
        int tt = i / E_, e = i % E_;
        float v = 0.f;
        if (e == is_[tt][0])      v = ps[tt][0];
        else if (e == is_[tt][1]) v = ps[tt][1];
        out[(size_t)tok0 * E_ + i] = v;
    }
    if (tid < TT * 2) {
        int tt = tid >> 1, s = tid & 1;
        out[(size_t)NTOK * E_ + (size_t)(tok0 + tt) * 2 + s] = (float)is_[tt][s];
    }
    if (tid == 0) {
        float es = 0.f;
        #pragma unroll
        for (int tt = 0; tt < TT; ++tt) es += entArr[tt];
        atomicAdd(&wsF[WS_ENT], es);
        unsigned* lu = (unsigned*)(wsF + WS_LOAD);
        #pragma unroll
        for (int e = 0; e < E_; ++e)
            if (loadLds[e]) atomicAdd(&lu[e], loadLds[e]);
    }
}

__global__ void finalize_kernel(const float* __restrict__ wsF,
                                float* __restrict__ out)
{
    if (threadIdx.x == 0 && blockIdx.x == 0) {
        const unsigned* lu = (const unsigned*)(wsF + WS_LOAD);
        double m = 0.0, l[E_];
        #pragma unroll
        for (int e = 0; e < E_; ++e) { l[e] = (double)lu[e]; m += l[e]; }
        m /= (double)E_;
        double var = 0.0;
        #pragma unroll
        for (int e = 0; e < E_; ++e) { double d = l[e] - m; var += d * d; }
        var /= (double)(E_ - 1);
        double stdl = sqrt(var);
        // importance = em.sum(0).mean(1) == 8*2/6 for every t -> std == 0 exactly
        double ent = (double)wsF[WS_ENT] / (double)NTOK;
        out[(size_t)NTOK * E_ + (size_t)NTOK * 2] = (float)(0.1 * ent + 0.2 * stdl);
    }
}

extern "C" void kernel_launch(void* const* d_in, const int* in_sizes, int n_in,
                              void* d_out, int out_size, void* d_ws, size_t ws_size,
                              hipStream_t stream)
{
    const float* x            = (const float*)d_in[0];
    const float* noise        = (const float*)d_in[1];
    const int*   expert_types = (const int*)  d_in[2];
    const float* type_emb     = (const float*)d_in[3];
    const float* nw1          = (const float*)d_in[4];
    const float* nb1          = (const float*)d_in[5];
    const float* nw2          = (const float*)d_in[6];
    const float* nb2          = (const float*)d_in[7];
    const float* rw1          = (const float*)d_in[8];
    const float* rb1          = (const float*)d_in[9];
    const float* rw2          = (const float*)d_in[10];
    const float* rb2          = (const float*)d_in[11];
    const float* temperature  = (const float*)d_in[12];
    float* out = (float*)d_out;
    float* wsF = (float*)d_ws;

    prep_kernel<<<10, 256, 0, stream>>>(type_emb, rw1, rb1, rw2, rb2, temperature, wsF);
    router_main<<<NTOK / TT, 256, 0, stream>>>(x, noise, expert_types,
                                               nw1, nb1, nw2, nb2, rw1, wsF, out);
    finalize_kernel<<<1, 64, 0, stream>>>(wsF, out);
}

// Round 6
// 258.080 us; speedup vs baseline: 1.2988x; 1.1577x over previous
//
#include <hip/hip_runtime.h>
#include <math.h>

#define B_ 8
#define T_ 4096
#define D_ 192
#define E_ 6
#define H_ 768            // 4*D
#define NTOK (B_*T_)      // 32768
#define TT 16             // tokens per block
#define NT 3              // number of expert types

// ws float-offset layout
#define WS_TPART 0                  // 3*768 (rb1 folded in)
#define WS_W2M   (NT*H_)            // 768
#define WS_TEMP  (WS_W2M + H_)      // 1
#define WS_RB2M  (WS_TEMP + 1)      // 1
#define WS_ENT   (WS_RB2M + 1)      // 1 (float accumulator, zeroed each call)
#define WS_LOAD  (WS_ENT + 1)       // 6 uints (zeroed each call)

// Fast erf (Abramowitz-Stegun 7.1.26): |err| <= 1.5e-7, single path.
__device__ __forceinline__ float gelu_f(float v) {
    float x  = v * 0.70710678118654752440f;
    float ax = fabsf(x);
    float t  = __builtin_amdgcn_rcpf(fmaf(0.3275911f, ax, 1.0f));   // v_rcp_f32
    float y  = t * fmaf(t, fmaf(t, fmaf(t, fmaf(t, 1.061405429f, -1.453152027f),
                                         1.421413741f), -0.284496736f), 0.254829592f);
    float em = __expf(-ax * ax);                                    // v_exp_f32 path
    float er = fmaf(-y, em, 1.0f);                                  // erf(|x|)
    er = copysignf(er, x);
    return 0.5f * v * (1.0f + er);
}
__device__ __forceinline__ float softplus_f(float x) {
    return fmaxf(x, 0.0f) + log1pf(expf(-fabsf(x)));
}

__global__ __launch_bounds__(256) void prep_kernel(
    const float* __restrict__ type_emb,    // (3, 384)
    const float* __restrict__ rw1,         // (576, 768)
    const float* __restrict__ rb1,         // (768)
    const float* __restrict__ rw2,         // (768, 6)
    const float* __restrict__ rb2,         // (6)
    const float* __restrict__ temperature, // (1)
    float* __restrict__ wsF)
{
    int blk = blockIdx.x, tid = threadIdx.x;
    if (blk < 9) {
        int o = blk * 256 + tid;          // 0..2303
        int c = o / H_, j = o % H_;
        float s = rb1[j];
        const float* te = type_emb + c * (2 * D_);
        #pragma unroll 4
        for (int k = 0; k < 2 * D_; ++k)
            s = fmaf(te[k], rw1[(size_t)(D_ + k) * H_ + j], s);
        wsF[WS_TPART + o] = s;
    } else {
        for (int j = tid; j < H_; j += 256) {
            float s = 0.f;
            #pragma unroll
            for (int e = 0; e < E_; ++e) s += rw2[(size_t)j * E_ + e];
            wsF[WS_W2M + j] = s * (1.0f / 6.0f);
        }
        if (tid == 0) {
            float decay = (float)pow(0.95, (double)(T_ / 100));   // 0.95^40
            float tv = temperature[0] * decay;
            tv = fminf(fmaxf(tv, 0.05f), 3.0f);
            wsF[WS_TEMP] = tv;
            float rs = 0.f;
            #pragma unroll
            for (int e = 0; e < E_; ++e) rs += rb2[e];
            wsF[WS_RB2M] = rs * (1.0f / 6.0f);
            wsF[WS_ENT] = 0.f;
            unsigned* lu = (unsigned*)(wsF + WS_LOAD);
            #pragma unroll
            for (int e = 0; e < E_; ++e) lu[e] = 0u;
        }
    }
}

// R6: k-loop start rotated per block (32 phases within each XCD) so resident
// blocks stream DIFFERENT rw1 cache lines at any instant. R1-R5 all read the
// same lines in lockstep -> L2 hot-line queueing (~600-1100 cy/iter stall,
// occupancy-invariant ~300us). Accumulation order change is f32-benign (~1e-6).
__global__ __launch_bounds__(256, 4) void router_main(
    const float* __restrict__ x,            // (32768, 192)
    const float* __restrict__ noise,        // (32768, 6)
    const int*   __restrict__ expert_types, // (6)
    const float* __restrict__ nw1,          // (192, 12)
    const float* __restrict__ nb1,          // (12)
    const float* __restrict__ nw2,          // (12, 6)
    const float* __restrict__ nb2,          // (6)
    const float* __restrict__ rw1,          // wx = rows [0,192)
    float* __restrict__ wsF,
    float* __restrict__ out)                // p | idx(float) | aux
{
    __shared__ float xsT[D_][TT];       // 12 KB, transposed x tile (rows 64B-aligned)
    __shared__ float red[NT * TT][4];   // per-wave partials
    __shared__ float logits[TT][NT];
    __shared__ float h1[TT][12];
    __shared__ float noisy[TT][E_];
    __shared__ float ps[TT][2];
    __shared__ int   is_[TT][2];
    __shared__ float entArr[TT];
    __shared__ unsigned loadLds[E_];

    int tid = threadIdx.x;
    int tok0 = blockIdx.x * TT;
    int wave = tid >> 6, lane = tid & 63;

    // ---- stage x tile (coalesced global read, transposed LDS write)
    for (int i = tid; i < TT * D_; i += 256) {
        int t = i / D_, k = i % D_;
        xsT[k][t] = x[(size_t)tok0 * D_ + i];
    }
    if (tid < E_) loadLds[tid] = 0u;
    __syncthreads();

    // ---- phase 1: xp(16x768) = xtile(16x192) @ wx(192x768), accs in registers.
    float a0[TT], a1[TT], a2[TT];
    #pragma unroll
    for (int t = 0; t < TT; ++t) { a0[t] = 0.f; a1[t] = 0.f; a2[t] = 0.f; }

    const float* __restrict__ wcol = rw1 + tid;
    // 32 k-phases, stride 6, distinct across the blocks co-resident on one XCD
    // (blockIdx -> XCD is round-robin mod 8, so bid>>3 enumerates within-XCD peers).
    int k0 = ((blockIdx.x >> 3) & 31) * 6;

#define K_BODY(k)                                                              \
    {                                                                          \
        float w0 = wcol[(size_t)(k) * H_];                                     \
        float w1 = wcol[(size_t)(k) * H_ + 256];                               \
        float w2 = wcol[(size_t)(k) * H_ + 512];                               \
        const float4* xr = reinterpret_cast<const float4*>(&xsT[(k)][0]);      \
        float4 xv0 = xr[0], xv1 = xr[1], xv2 = xr[2], xv3 = xr[3];             \
        const float xv[TT] = { xv0.x, xv0.y, xv0.z, xv0.w,                     \
                               xv1.x, xv1.y, xv1.z, xv1.w,                     \
                               xv2.x, xv2.y, xv2.z, xv2.w,                     \
                               xv3.x, xv3.y, xv3.z, xv3.w };                   \
        _Pragma("unroll")                                                      \
        for (int t = 0; t < TT; ++t) {                                         \
            a0[t] = fmaf(xv[t], w0, a0[t]);                                    \
            a1[t] = fmaf(xv[t], w1, a1[t]);                                    \
            a2[t] = fmaf(xv[t], w2, a2[t]);                                    \
        }                                                                      \
    }

    #pragma unroll 2
    for (int k = k0; k < D_; ++k) K_BODY(k)
    #pragma unroll 2
    for (int k = 0; k < k0; ++k)  K_BODY(k)
#undef K_BODY

    // ---- phase 2 (fused): logits[t][c] = sum_j gelu(xp+tp)*w2m + rb2m
    float w2r0 = wsF[WS_W2M + tid];
    float w2r1 = wsF[WS_W2M + tid + 256];
    float w2r2 = wsF[WS_W2M + tid + 512];
    #pragma unroll
    for (int c = 0; c < NT; ++c) {
        float tp0 = wsF[WS_TPART + c * H_ + tid];
        float tp1 = wsF[WS_TPART + c * H_ + tid + 256];
        float tp2 = wsF[WS_TPART + c * H_ + tid + 512];
        #pragma unroll
        for (int t = 0; t < TT; ++t) {
            float g = gelu_f(a0[t] + tp0) * w2r0
                    + gelu_f(a1[t] + tp1) * w2r1
                    + gelu_f(a2[t] + tp2) * w2r2;
            #pragma unroll
            for (int off = 32; off; off >>= 1) g += __shfl_xor(g, off, 64);
            if (lane == 0) red[c * TT + t][wave] = g;
        }
    }
    __syncthreads();
    float rb2m = wsF[WS_RB2M];
    if (tid < NT * TT) {
        int c = tid / TT, t = tid % TT;
        logits[t][c] = red[tid][0] + red[tid][1] + red[tid][2] + red[tid][3] + rb2m;
    }
    __syncthreads();

    // ---- phase 3: noise MLP, noisy logits, top-2, softmax, entropy
    int t = tid >> 4, j = tid & 15;       // 16 threads per token
    if (j < 12) {
        float s = nb1[j];
        #pragma unroll 4
        for (int k = 0; k < D_; ++k) s = fmaf(xsT[k][t], nw1[k * 12 + j], s);
        h1[t][j] = gelu_f(s);
    }
    __syncthreads();
    float temp = wsF[WS_TEMP];
    if (j < E_) {
        float s = nb2[j];
        #pragma unroll
        for (int i = 0; i < 12; ++i) s = fmaf(h1[t][i], nw2[i * E_ + j], s);
        float nsc = softplus_f(softplus_f(s));
        int ety = expert_types[j];
        float nv = logits[t][ety] + ((ety == 1) ? 0.3f : 0.0f)
                 + temp * (noise[(size_t)(tok0 + t) * E_ + j] * nsc);
        noisy[t][j] = nv;
    }
    __syncthreads();
    if (j == 0) {
        // top-2, ties -> lower index first (strict > keeps earliest)
        float v1 = -1e30f; int i1 = 0;
        #pragma unroll
        for (int e = 0; e < E_; ++e) {
            float v = noisy[t][e];
            if (v > v1) { v1 = v; i1 = e; }
        }
        float v2 = -1e30f; int i2 = 0;
        #pragma unroll
        for (int e = 0; e < E_; ++e) {
            if (e == i1) continue;
            float v = noisy[t][e];
            if (v > v2) { v2 = v; i2 = e; }
        }
        float e2 = expf(v2 - v1);
        float denom = 1.0f + e2;
        float p1 = 1.0f / denom;
        float p2 = e2 / denom;
        ps[t][0] = p1; ps[t][1] = p2;
        is_[t][0] = i1; is_[t][1] = i2;
        entArr[t] = -(p1 * logf(p1 + 1e-8f) + p2 * logf(p2 + 1e-8f));
        atomicAdd(&loadLds[i1], 1u);
        atomicAdd(&loadLds[i2], 1u);
    }
    __syncthreads();

    // ---- outputs
    for (int i = tid; i < TT * E_; i += 256) {
        int tt = i / E_, e = i % E_;
        float v = 0.f;
        if (e == is_[tt][0])      v = ps[tt][0];
        else if (e == is_[tt][1]) v = ps[tt][1];
        out[(size_t)tok0 * E_ + i] = v;
    }
    if (tid < TT * 2) {
        int tt = tid >> 1, s = tid & 1;
        out[(size_t)NTOK * E_ + (size_t)(tok0 + tt) * 2 + s] = (float)is_[tt][s];
    }
    if (tid == 0) {
        float es = 0.f;
        #pragma unroll
        for (int tt = 0; tt < TT; ++tt) es += entArr[tt];
        atomicAdd(&wsF[WS_ENT], es);
        unsigned* lu = (unsigned*)(wsF + WS_LOAD);
        #pragma unroll
        for (int e = 0; e < E_; ++e)
            if (loadLds[e]) atomicAdd(&lu[e], loadLds[e]);
    }
}

__global__ void finalize_kernel(const float* __restrict__ wsF,
                                float* __restrict__ out)
{
    if (threadIdx.x == 0 && blockIdx.x == 0) {
        const unsigned* lu = (const unsigned*)(wsF + WS_LOAD);
        double m = 0.0, l[E_];
        #pragma unroll
        for (int e = 0; e < E_; ++e) { l[e] = (double)lu[e]; m += l[e]; }
        m /= (double)E_;
        double var = 0.0;
        #pragma unroll
        for (int e = 0; e < E_; ++e) { double d = l[e] - m; var += d * d; }
        var /= (double)(E_ - 1);
        double stdl = sqrt(var);
        // importance = em.sum(0).mean(1) == 8*2/6 for every t -> std == 0 exactly
        double ent = (double)wsF[WS_ENT] / (double)NTOK;
        out[(size_t)NTOK * E_ + (size_t)NTOK * 2] = (float)(0.1 * ent + 0.2 * stdl);
    }
}

extern "C" void kernel_launch(void* const* d_in, const int* in_sizes, int n_in,
                              void* d_out, int out_size, void* d_ws, size_t ws_size,
                              hipStream_t stream)
{
    const float* x            = (const float*)d_in[0];
    const float* noise        = (const float*)d_in[1];
    const int*   expert_types = (const int*)  d_in[2];
    const float* type_emb     = (const float*)d_in[3];
    const float* nw1          = (const float*)d_in[4];
    const float* nb1          = (const float*)d_in[5];
    const float* nw2          = (const float*)d_in[6];
    const float* nb2          = (const float*)d_in[7];
    const float* rw1          = (const float*)d_in[8];
    const float* rb1          = (const float*)d_in[9];
    const float* rw2          = (const float*)d_in[10];
    const float* rb2          = (const float*)d_in[11];
    const float* temperature  = (const float*)d_in[12];
    float* out = (float*)d_out;
    float* wsF = (float*)d_ws;

    prep_kernel<<<10, 256, 0, stream>>>(type_emb, rw1, rb1, rw2, rb2, temperature, wsF);
    router_main<<<NTOK / TT, 256, 0, stream>>>(x, noise, expert_types,
                                               nw1, nb1, nw2, nb2, rw1, wsF, out);
    finalize_kernel<<<1, 64, 0, stream>>>(wsF, out);
}

// Round 7
// 250.701 us; speedup vs baseline: 1.3370x; 1.0294x over previous
//
#include <hip/hip_runtime.h>
#include <math.h>

#define B_ 8
#define T_ 4096
#define D_ 192
#define E_ 6
#define H_ 768            // 4*D
#define NTOK (B_*T_)      // 32768
#define TT 16             // tokens per block
#define NT 3              // number of expert types

// ws float-offset layout
#define WS_TPART 0                  // 3*768 (rb1 folded in)
#define WS_W2M   (NT*H_)            // 768
#define WS_TEMP  (WS_W2M + H_)      // 1
#define WS_RB2M  (WS_TEMP + 1)      // 1
#define WS_ENT   (WS_RB2M + 1)      // 1 (float accumulator, zeroed each call)
#define WS_LOAD  (WS_ENT + 1)       // 6 uints (zeroed each call)

// Fast erf (Abramowitz-Stegun 7.1.26): |err| <= 1.5e-7, single path.
__device__ __forceinline__ float gelu_f(float v) {
    float x  = v * 0.70710678118654752440f;
    float ax = fabsf(x);
    float t  = __builtin_amdgcn_rcpf(fmaf(0.3275911f, ax, 1.0f));   // v_rcp_f32
    float y  = t * fmaf(t, fmaf(t, fmaf(t, fmaf(t, 1.061405429f, -1.453152027f),
                                         1.421413741f), -0.284496736f), 0.254829592f);
    float em = __expf(-ax * ax);                                    // v_exp_f32 path
    float er = fmaf(-y, em, 1.0f);                                  // erf(|x|)
    er = copysignf(er, x);
    return 0.5f * v * (1.0f + er);
}
__device__ __forceinline__ float softplus_f(float x) {
    return fmaxf(x, 0.0f) + log1pf(expf(-fabsf(x)));
}

__global__ __launch_bounds__(256) void prep_kernel(
    const float* __restrict__ type_emb,    // (3, 384)
    const float* __restrict__ rw1,         // (576, 768)
    const float* __restrict__ rb1,         // (768)
    const float* __restrict__ rw2,         // (768, 6)
    const float* __restrict__ rb2,         // (6)
    const float* __restrict__ temperature, // (1)
    float* __restrict__ wsF)
{
    int blk = blockIdx.x, tid = threadIdx.x;
    if (blk < 9) {
        int o = blk * 256 + tid;          // 0..2303
        int c = o / H_, j = o % H_;
        float s = rb1[j];
        const float* te = type_emb + c * (2 * D_);
        #pragma unroll 4
        for (int k = 0; k < 2 * D_; ++k)
            s = fmaf(te[k], rw1[(size_t)(D_ + k) * H_ + j], s);
        wsF[WS_TPART + o] = s;
    } else {
        for (int j = tid; j < H_; j += 256) {
            float s = 0.f;
            #pragma unroll
            for (int e = 0; e < E_; ++e) s += rw2[(size_t)j * E_ + e];
            wsF[WS_W2M + j] = s * (1.0f / 6.0f);
        }
        if (tid == 0) {
            float decay = (float)pow(0.95, (double)(T_ / 100));   // 0.95^40
            float tv = temperature[0] * decay;
            tv = fminf(fmaxf(tv, 0.05f), 3.0f);
            wsF[WS_TEMP] = tv;
            float rs = 0.f;
            #pragma unroll
            for (int e = 0; e < E_; ++e) rs += rb2[e];
            wsF[WS_RB2M] = rs * (1.0f / 6.0f);
            wsF[WS_ENT] = 0.f;
            unsigned* lu = (unsigned*)(wsF + WS_LOAD);
            #pragma unroll
            for (int e = 0; e < E_; ++e) lu[e] = 0u;
        }
    }
}

// R7: per-WAVE k-phase rotation (256 distinct phases chip-wide, vs 32 per-block
// in R6) — each wave streams a different rw1 row at any instant, minimizing L2
// hot-line queueing. k0 is wave-uniform -> scalar loop bounds, no divergence.
// (256,5): 5 waves/EU, combined reg cap 102 >= ~90 live (R2's spill was a
// 64-cap vs ~110 live — different regime).
__global__ __launch_bounds__(256, 5) void router_main(
    const float* __restrict__ x,            // (32768, 192)
    const float* __restrict__ noise,        // (32768, 6)
    const int*   __restrict__ expert_types, // (6)
    const float* __restrict__ nw1,          // (192, 12)
    const float* __restrict__ nb1,          // (12)
    const float* __restrict__ nw2,          // (12, 6)
    const float* __restrict__ nb2,          // (6)
    const float* __restrict__ rw1,          // wx = rows [0,192)
    float* __restrict__ wsF,
    float* __restrict__ out)                // p | idx(float) | aux
{
    __shared__ float xsT[D_][TT];       // 12 KB, transposed x tile (rows 64B-aligned)
    __shared__ float red[NT * TT][4];   // per-wave partials
    __shared__ float logits[TT][NT];
    __shared__ float h1[TT][12];
    __shared__ float noisy[TT][E_];
    __shared__ float ps[TT][2];
    __shared__ int   is_[TT][2];
    __shared__ float entArr[TT];
    __shared__ unsigned loadLds[E_];

    int tid = threadIdx.x;
    int tok0 = blockIdx.x * TT;
    int wave = tid >> 6, lane = tid & 63;

    // ---- stage x tile (coalesced global read, transposed LDS write)
    for (int i = tid; i < TT * D_; i += 256) {
        int t = i / D_, k = i % D_;
        xsT[k][t] = x[(size_t)tok0 * D_ + i];
    }
    if (tid < E_) loadLds[tid] = 0u;
    __syncthreads();

    // ---- phase 1: xp(16x768) = xtile(16x192) @ wx(192x768), accs in registers.
    float a0[TT], a1[TT], a2[TT];
    #pragma unroll
    for (int t = 0; t < TT; ++t) { a0[t] = 0.f; a1[t] = 0.f; a2[t] = 0.f; }

    const float* __restrict__ wcol = rw1 + tid;
    // 64 phases x stride 3, distinct per (block-within-XCD, wave).
    int k0 = ((((blockIdx.x >> 3) << 2) + wave) & 63) * 3;

#define K_BODY(k)                                                              \
    {                                                                          \
        float w0 = wcol[(size_t)(k) * H_];                                     \
        float w1 = wcol[(size_t)(k) * H_ + 256];                               \
        float w2 = wcol[(size_t)(k) * H_ + 512];                               \
        const float4* xr = reinterpret_cast<const float4*>(&xsT[(k)][0]);      \
        float4 xv0 = xr[0], xv1 = xr[1], xv2 = xr[2], xv3 = xr[3];             \
        const float xv[TT] = { xv0.x, xv0.y, xv0.z, xv0.w,                     \
                               xv1.x, xv1.y, xv1.z, xv1.w,                     \
                               xv2.x, xv2.y, xv2.z, xv2.w,                     \
                               xv3.x, xv3.y, xv3.z, xv3.w };                   \
        _Pragma("unroll")                                                      \
        for (int t = 0; t < TT; ++t) {                                         \
            a0[t] = fmaf(xv[t], w0, a0[t]);                                    \
            a1[t] = fmaf(xv[t], w1, a1[t]);                                    \
            a2[t] = fmaf(xv[t], w2, a2[t]);                                    \
        }                                                                      \
    }

    #pragma unroll 2
    for (int k = k0; k < D_; ++k) K_BODY(k)
    #pragma unroll 2
    for (int k = 0; k < k0; ++k)  K_BODY(k)
#undef K_BODY

    // ---- phase 2 (fused): logits[t][c] = sum_j gelu(xp+tp)*w2m + rb2m
    float w2r0 = wsF[WS_W2M + tid];
    float w2r1 = wsF[WS_W2M + tid + 256];
    float w2r2 = wsF[WS_W2M + tid + 512];
    #pragma unroll
    for (int c = 0; c < NT; ++c) {
        float tp0 = wsF[WS_TPART + c * H_ + tid];
        float tp1 = wsF[WS_TPART + c * H_ + tid + 256];
        float tp2 = wsF[WS_TPART + c * H_ + tid + 512];
        #pragma unroll
        for (int t = 0; t < TT; ++t) {
            float g = gelu_f(a0[t] + tp0) * w2r0
                    + gelu_f(a1[t] + tp1) * w2r1
                    + gelu_f(a2[t] + tp2) * w2r2;
            #pragma unroll
            for (int off = 32; off; off >>= 1) g += __shfl_xor(g, off, 64);
            if (lane == 0) red[c * TT + t][wave] = g;
        }
    }
    __syncthreads();
    float rb2m = wsF[WS_RB2M];
    if (tid < NT * TT) {
        int c = tid / TT, t = tid % TT;
        logits[t][c] = red[tid][0] + red[tid][1] + red[tid][2] + red[tid][3] + rb2m;
    }
    __syncthreads();

    // ---- phase 3: noise MLP, noisy logits, top-2, softmax, entropy
    int t = tid >> 4, j = tid & 15;       // 16 threads per token
    if (j < 12) {
        float s = nb1[j];
        #pragma unroll 4
        for (int k = 0; k < D_; ++k) s = fmaf(xsT[k][t], nw1[k * 12 + j], s);
        h1[t][j] = gelu_f(s);
    }
    __syncthreads();
    float temp = wsF[WS_TEMP];
    if (j < E_) {
        float s = nb2[j];
        #pragma unroll
        for (int i = 0; i < 12; ++i) s = fmaf(h1[t][i], nw2[i * E_ + j], s);
        float nsc = softplus_f(softplus_f(s));
        int ety = expert_types[j];
        float nv = logits[t][ety] + ((ety == 1) ? 0.3f : 0.0f)
                 + temp * (noise[(size_t)(tok0 + t) * E_ + j] * nsc);
        noisy[t][j] = nv;
    }
    __syncthreads();
    if (j == 0) {
        // top-2, ties -> lower index first (strict > keeps earliest)
        float v1 = -1e30f; int i1 = 0;
        #pragma unroll
        for (int e = 0; e < E_; ++e) {
            float v = noisy[t][e];
            if (v > v1) { v1 = v; i1 = e; }
        }
        float v2 = -1e30f; int i2 = 0;
        #pragma unroll
        for (int e = 0; e < E_; ++e) {
            if (e == i1) continue;
            float v = noisy[t][e];
            if (v > v2) { v2 = v; i2 = e; }
        }
        float e2 = expf(v2 - v1);
        float denom = 1.0f + e2;
        float p1 = 1.0f / denom;
        float p2 = e2 / denom;
        ps[t][0] = p1; ps[t][1] = p2;
        is_[t][0] = i1; is_[t][1] = i2;
        entArr[t] = -(p1 * logf(p1 + 1e-8f) + p2 * logf(p2 + 1e-8f));
        atomicAdd(&loadLds[i1], 1u);
        atomicAdd(&loadLds[i2], 1u);
    }
    __syncthreads();

    // ---- outputs
    for (int i = tid; i < TT * E_; i += 256) {
        int tt = i / E_, e = i % E_;
        float v = 0.f;
        if (e == is_[tt][0])      v = ps[tt][0];
        else if (e == is_[tt][1]) v = ps[tt][1];
        out[(size_t)tok0 * E_ + i] = v;
    }
    if (tid < TT * 2) {
        int tt = tid >> 1, s = tid & 1;
        out[(size_t)NTOK * E_ + (size_t)(tok0 + tt) * 2 + s] = (float)is_[tt][s];
    }
    if (tid == 0) {
        float es = 0.f;
        #pragma unroll
        for (int tt = 0; tt < TT; ++tt) es += entArr[tt];
        atomicAdd(&wsF[WS_ENT], es);
        unsigned* lu = (unsigned*)(wsF + WS_LOAD);
        #pragma unroll
        for (int e = 0; e < E_; ++e)
            if (loadLds[e]) atomicAdd(&lu[e], loadLds[e]);
    }
}

__global__ void finalize_kernel(const float* __restrict__ wsF,
                                float* __restrict__ out)
{
    if (threadIdx.x == 0 && blockIdx.x == 0) {
        const unsigned* lu = (const unsigned*)(wsF + WS_LOAD);
        double m = 0.0, l[E_];
        #pragma unroll
        for (int e = 0; e < E_; ++e) { l[e] = (double)lu[e]; m += l[e]; }
        m /= (double)E_;
        double var = 0.0;
        #pragma unroll
        for (int e = 0; e < E_; ++e) { double d = l[e] - m; var += d * d; }
        var /= (double)(E_ - 1);
        double stdl = sqrt(var);
        // importance = em.sum(0).mean(1) == 8*2/6 for every t -> std == 0 exactly
        double ent = (double)wsF[WS_ENT] / (double)NTOK;
        out[(size_t)NTOK * E_ + (size_t)NTOK * 2] = (float)(0.1 * ent + 0.2 * stdl);
    }
}

extern "C" void kernel_launch(void* const* d_in, const int* in_sizes, int n_in,
                              void* d_out, int out_size, void* d_ws, size_t ws_size,
                              hipStream_t stream)
{
    const float* x            = (const float*)d_in[0];
    const float* noise        = (const float*)d_in[1];
    const int*   expert_types = (const int*)  d_in[2];
    const float* type_emb     = (const float*)d_in[3];
    const float* nw1          = (const float*)d_in[4];
    const float* nb1          = (const float*)d_in[5];
    const float* nw2          = (const float*)d_in[6];
    const float* nb2          = (const float*)d_in[7];
    const float* rw1          = (const float*)d_in[8];
    const float* rb1          = (const float*)d_in[9];
    const float* rw2          = (const float*)d_in[10];
    const float* rb2          = (const float*)d_in[11];
    const float* temperature  = (const float*)d_in[12];
    float* out = (float*)d_out;
    float* wsF = (float*)d_ws;

    prep_kernel<<<10, 256, 0, stream>>>(type_emb, rw1, rb1, rw2, rb2, temperature, wsF);
    router_main<<<NTOK / TT, 256, 0, stream>>>(x, noise, expert_types,
                                               nw1, nb1, nw2, nb2, rw1, wsF, out);
    finalize_kernel<<<1, 64, 0, stream>>>(wsF, out);
}

// Round 8
// 148.970 us; speedup vs baseline: 2.2500x; 1.6829x over previous
//
#include <hip/hip_runtime.h>
#include <math.h>

#define B_ 8
#define T_ 4096
#define D_ 192
#define E_ 6
#define H_ 768            // 4*D
#define NTOK (B_*T_)      // 32768
#define NT 3              // expert types
#define TPB 64            // tokens per block
#define NBLK (NTOK/TPB)   // 512
#define NNT 49            // 48 rw1 column-tiles + 1 padded nw1 tile
#define NKS 6             // K steps of 32 (K=192)

// ws float-offset layout
#define WS_TPART 0        // 3*768 (rb1 folded in)
#define WS_W2M   2304     // 768
#define WS_TEMP  3072
#define WS_RB2M  3073
#define WS_ENT   3074
#define WS_LOAD  3075     // 6 uints
#define WS_BP    4096     // bf16 fragment pack: 49 * 9216 ushorts (903 KB)

typedef float  f32x4  __attribute__((ext_vector_type(4)));
typedef short  bf16x8 __attribute__((ext_vector_type(8)));

__device__ __forceinline__ ushort bf16rn(float f) {   // round-to-nearest-even bf16
    unsigned u = __float_as_uint(f);
    return (ushort)((u + 0x7FFFu + ((u >> 16) & 1u)) >> 16);
}

// Fast erf (Abramowitz-Stegun 7.1.26): |err| <= 1.5e-7 (validated R4-R7).
__device__ __forceinline__ float gelu_f(float v) {
    float x  = v * 0.70710678118654752440f;
    float ax = fabsf(x);
    float t  = __builtin_amdgcn_rcpf(fmaf(0.3275911f, ax, 1.0f));
    float y  = t * fmaf(t, fmaf(t, fmaf(t, fmaf(t, 1.061405429f, -1.453152027f),
                                         1.421413741f), -0.284496736f), 0.254829592f);
    float em = __expf(-ax * ax);
    float er = fmaf(-y, em, 1.0f);
    er = copysignf(er, x);
    return 0.5f * v * (1.0f + er);
}
__device__ __forceinline__ float softplus_f(float x) {
    return fmaxf(x, 0.0f) + log1pf(expf(-fabsf(x)));
}

// prep: blocks 0..48 pack B fragments (3-way bf16 split, MFMA lane order);
// blocks 49..57 tpart; block 58 w2m + scalars.
__global__ __launch_bounds__(256) void prep_kernel(
    const float* __restrict__ type_emb,    // (3, 384)
    const float* __restrict__ rw1,         // (576, 768)
    const float* __restrict__ rb1,         // (768)
    const float* __restrict__ rw2,         // (768, 6)
    const float* __restrict__ rb2,         // (6)
    const float* __restrict__ temperature, // (1)
    const float* __restrict__ nw1,         // (192, 12)
    float* __restrict__ wsF)
{
    int blk = blockIdx.x, tid = threadIdx.x;
    if (blk < NNT) {
        int nt = blk;
        ushort* Bp = (ushort*)(wsF + WS_BP);
        int col = tid & 15;                         // coalesced reads: 16 cols/row
        for (int kr = tid >> 4; kr < D_; kr += 16) {
            float a;
            if (nt < 48) a = rw1[(size_t)kr * H_ + nt * 16 + col];
            else         a = (col < 12) ? nw1[kr * 12 + col] : 0.0f;
            ushort s1 = bf16rn(a);  float f1 = __uint_as_float((unsigned)s1 << 16);
            float r1 = a - f1;
            ushort s2 = bf16rn(r1); float f2 = __uint_as_float((unsigned)s2 << 16);
            float r2 = r1 - f2;
            ushort s3 = bf16rn(r2);
            // B-frag layout: lane l holds B[k= ks*32+(l>>4)*8+i][col= l&15]
            int ks = kr >> 5, kg = (kr >> 3) & 3, i = kr & 7;
            int l  = (kg << 4) | col;
            size_t base = (size_t)nt * 9216 + (size_t)((ks * 3) * 64 + l) * 8 + i;
            Bp[base]        = s1;                   // spl 0
            Bp[base + 512]  = s2;                   // spl 1 (+64 lanes*8)
            Bp[base + 1024] = s3;                   // spl 2
        }
    } else if (blk < NNT + 9) {
        int o = (blk - NNT) * 256 + tid;            // 0..2303
        int c = o / H_, j = o % H_;
        float s = rb1[j];
        const float* te = type_emb + c * (2 * D_);
        #pragma unroll 4
        for (int k = 0; k < 2 * D_; ++k)
            s = fmaf(te[k], rw1[(size_t)(D_ + k) * H_ + j], s);
        wsF[WS_TPART + o] = s;
    } else {
        for (int j = tid; j < H_; j += 256) {
            float s = 0.f;
            #pragma unroll
            for (int e = 0; e < E_; ++e) s += rw2[(size_t)j * E_ + e];
            wsF[WS_W2M + j] = s * (1.0f / 6.0f);
        }
        if (tid == 0) {
            float decay = (float)pow(0.95, (double)(T_ / 100));   // 0.95^40
            float tv = temperature[0] * decay;
            wsF[WS_TEMP] = fminf(fmaxf(tv, 0.05f), 3.0f);
            float rs = 0.f;
            #pragma unroll
            for (int e = 0; e < E_; ++e) rs += rb2[e];
            wsF[WS_RB2M] = rs * (1.0f / 6.0f);
            wsF[WS_ENT] = 0.f;
            unsigned* lu = (unsigned*)(wsF + WS_LOAD);
            #pragma unroll
            for (int e = 0; e < E_; ++e) lu[e] = 0u;
        }
    }
}

// R8: phase 1+2 on the matrix pipe. 3-way bf16 split, 6 products -> residual
// ~2^-27 (logit err ~2e-9, far below the validated flip margin). nw1 layer-1
// is tile nt=48. Grid 512 -> 2 blocks/CU (8 waves/CU); regs free up to 256.
__global__ __launch_bounds__(256, 2) void router_mfma(
    const float* __restrict__ x,            // (32768, 192)
    const float* __restrict__ noise,        // (32768, 6)
    const int*   __restrict__ expert_types, // (6)
    const float* __restrict__ nb1,          // (12)
    const float* __restrict__ nw2,          // (12, 6)
    const float* __restrict__ nb2,          // (6)
    float* __restrict__ wsF,
    float* __restrict__ out)
{
    __shared__ float4 Bst[2][1152];     // 36 KB double-buffered B tile
    __shared__ float tpL[NT * H_];      // 9 KB
    __shared__ float w2L[H_];           // 3 KB
    __shared__ float logitsL[TPB][NT];
    __shared__ float h1L[TPB][12];
    __shared__ float noisyL[TPB][E_];
    __shared__ float psL[TPB][2];
    __shared__ int   isL[TPB][2];
    __shared__ float entL[TPB];
    __shared__ unsigned loadL[E_];

    int tid = threadIdx.x;
    int wave = tid >> 6, lane = tid & 63;
    int tok0 = blockIdx.x * TPB;
    int jc = lane & 15;

    for (int i = tid; i < NT * H_; i += 256) tpL[i] = wsF[WS_TPART + i];
    for (int i = tid; i < H_; i += 256)      w2L[i] = wsF[WS_W2M + i];
    if (tid < E_) loadL[tid] = 0u;

    // ---- A fragments: lane holds row (lane&15) of its wave's 16-token tile,
    // k = ks*32 + (lane>>4)*8 + i. Split into 3 bf16 components (72 VGPR).
    int tok = tok0 + (wave << 4) + jc;
    int kg  = (lane >> 4) << 3;
    bf16x8 a1[NKS], a2[NKS], a3[NKS];
    #pragma unroll
    for (int ks = 0; ks < NKS; ++ks) {
        const float* xp = x + (size_t)tok * D_ + ks * 32 + kg;
        float4 v0 = *(const float4*)xp;
        float4 v1 = *(const float4*)(xp + 4);
        float f[8] = {v0.x, v0.y, v0.z, v0.w, v1.x, v1.y, v1.z, v1.w};
        #pragma unroll
        for (int i = 0; i < 8; ++i) {
            float a = f[i];
            ushort s1 = bf16rn(a);  float f1 = __uint_as_float((unsigned)s1 << 16);
            float r1 = a - f1;
            ushort s2 = bf16rn(r1); float f2 = __uint_as_float((unsigned)s2 << 16);
            float r2 = r1 - f2;
            a1[ks][i] = (short)s1; a2[ks][i] = (short)s2; a3[ks][i] = (short)bf16rn(r2);
        }
    }

    float la0[4] = {0,0,0,0}, la1[4] = {0,0,0,0}, la2[4] = {0,0,0,0};
    const ushort* Bp = (const ushort*)(wsF + WS_BP);
    int nt0 = blockIdx.x % NNT;    // rotate tile order (R6 lesson: decorrelate streams)

    float4 g0, g1, g2, g3, g4;     // T14 async-split staging registers
#define STAGE_LOAD(ntv) { \
    const float4* sp_ = (const float4*)(Bp + (size_t)(ntv) * 9216); \
    g0 = sp_[tid]; g1 = sp_[tid + 256]; g2 = sp_[tid + 512]; g3 = sp_[tid + 768]; \
    if (tid < 128) g4 = sp_[tid + 1024]; }
#define STAGE_WRITE(buf) { \
    (buf)[tid] = g0; (buf)[tid + 256] = g1; (buf)[tid + 512] = g2; (buf)[tid + 768] = g3; \
    if (tid < 128) (buf)[tid + 1024] = g4; }

    STAGE_LOAD(nt0);
    STAGE_WRITE(Bst[0]);
    __syncthreads();

    int cur = 0;
    for (int it = 0; it < NNT; ++it) {
        int nt = nt0 + it; if (nt >= NNT) nt -= NNT;
        if (it + 1 < NNT) { int ntn = nt + 1; if (ntn >= NNT) ntn -= NNT; STAGE_LOAD(ntn); }

        const bf16x8* bp = (const bf16x8*)&Bst[cur][0];
        f32x4 c0 = {0,0,0,0}, c1 = {0,0,0,0}, c2 = {0,0,0,0},
              c3 = {0,0,0,0}, c4 = {0,0,0,0}, c5 = {0,0,0,0};
        #pragma unroll
        for (int ks = 0; ks < NKS; ++ks) {
            bf16x8 b1 = bp[(ks * 3 + 0) * 64 + lane];
            bf16x8 b2 = bp[(ks * 3 + 1) * 64 + lane];
            bf16x8 b3 = bp[(ks * 3 + 2) * 64 + lane];
            c0 = __builtin_amdgcn_mfma_f32_16x16x32_bf16(a1[ks], b1, c0, 0, 0, 0);
            c1 = __builtin_amdgcn_mfma_f32_16x16x32_bf16(a1[ks], b2, c1, 0, 0, 0);
            c2 = __builtin_amdgcn_mfma_f32_16x16x32_bf16(a2[ks], b1, c2, 0, 0, 0);
            c3 = __builtin_amdgcn_mfma_f32_16x16x32_bf16(a2[ks], b2, c3, 0, 0, 0);
            c4 = __builtin_amdgcn_mfma_f32_16x16x32_bf16(a1[ks], b3, c4, 0, 0, 0);
            c5 = __builtin_amdgcn_mfma_f32_16x16x32_bf16(a3[ks], b1, c5, 0, 0, 0);
        }
        // D layout: row=(lane>>4)*4+r (token-local), col=lane&15 (j within tile)
        if (nt < 48) {
            int j = nt * 16 + jc;
            float w2v = w2L[j];
            float t0 = tpL[j], t1 = tpL[H_ + j], t2 = tpL[2 * H_ + j];
            #pragma unroll
            for (int r = 0; r < 4; ++r) {
                float xv = ((c0[r] + c1[r]) + (c2[r] + c3[r])) + (c4[r] + c5[r]);
                la0[r] += gelu_f(xv + t0) * w2v;
                la1[r] += gelu_f(xv + t1) * w2v;
                la2[r] += gelu_f(xv + t2) * w2v;
            }
        } else if (jc < 12) {
            float bb = nb1[jc];
            #pragma unroll
            for (int r = 0; r < 4; ++r) {
                float xv = ((c0[r] + c1[r]) + (c2[r] + c3[r])) + (c4[r] + c5[r]);
                int tl = (wave << 4) + ((lane >> 4) << 2) + r;
                h1L[tl][jc] = gelu_f(xv + bb);
            }
        }
        __syncthreads();
        if (it + 1 < NNT) STAGE_WRITE(Bst[cur ^ 1]);
        __syncthreads();
        cur ^= 1;
    }

    // ---- finish logits: butterfly over the 16 j-columns held by a lane group
    float rb2m = wsF[WS_RB2M];
    #pragma unroll
    for (int r = 0; r < 4; ++r) {
        float v0 = la0[r], v1 = la1[r], v2 = la2[r];
        #pragma unroll
        for (int off = 1; off < 16; off <<= 1) {
            v0 += __shfl_xor(v0, off, 64);
            v1 += __shfl_xor(v1, off, 64);
            v2 += __shfl_xor(v2, off, 64);
        }
        if (jc == 0) {
            int tl = (wave << 4) + ((lane >> 4) << 2) + r;
            logitsL[tl][0] = v0 + rb2m;
            logitsL[tl][1] = v1 + rb2m;
            logitsL[tl][2] = v2 + rb2m;
        }
    }
    __syncthreads();

    // ---- phase 3: noise MLP layer 2, noisy logits, top-2, softmax, entropy
    float temp = wsF[WS_TEMP];
    for (int idx = tid; idx < TPB * E_; idx += 256) {
        int t = idx / E_, e = idx - t * E_;
        float s = nb2[e];
        #pragma unroll
        for (int i2 = 0; i2 < 12; ++i2) s = fmaf(h1L[t][i2], nw2[i2 * E_ + e], s);
        float nsc = softplus_f(softplus_f(s));
        int ety = expert_types[e];
        noisyL[t][e] = logitsL[t][ety] + ((ety == 1) ? 0.3f : 0.0f)
                     + temp * (noise[(size_t)(tok0 + t) * E_ + e] * nsc);
    }
    __syncthreads();
    if (tid < TPB) {
        int t = tid;
        float v1 = -1e30f; int i1 = 0;
        #pragma unroll
        for (int e = 0; e < E_; ++e) {
            float v = noisyL[t][e];
            if (v > v1) { v1 = v; i1 = e; }
        }
        float v2 = -1e30f; int i2 = 0;
        #pragma unroll
        for (int e = 0; e < E_; ++e) {
            if (e == i1) continue;
            float v = noisyL[t][e];
            if (v > v2) { v2 = v; i2 = e; }
        }
        float e2 = expf(v2 - v1);
        float den = 1.0f + e2;
        float p1 = 1.0f / den, p2 = e2 / den;
        psL[t][0] = p1; psL[t][1] = p2;
        isL[t][0] = i1; isL[t][1] = i2;
        entL[t] = -(p1 * logf(p1 + 1e-8f) + p2 * logf(p2 + 1e-8f));
        atomicAdd(&loadL[i1], 1u);
        atomicAdd(&loadL[i2], 1u);
    }
    __syncthreads();
    for (int idx = tid; idx < TPB * E_; idx += 256) {
        int t = idx / E_, e = idx - t * E_;
        float v = 0.f;
        if (e == isL[t][0])      v = psL[t][0];
        else if (e == isL[t][1]) v = psL[t][1];
        out[(size_t)tok0 * E_ + idx] = v;
    }
    if (tid < TPB * 2) {
        int t = tid >> 1, s = tid & 1;
        out[(size_t)NTOK * E_ + (size_t)(tok0 + t) * 2 + s] = (float)isL[t][s];
    }
    if (tid == 0) {
        float es = 0.f;
        #pragma unroll
        for (int tt = 0; tt < TPB; ++tt) es += entL[tt];
        atomicAdd(&wsF[WS_ENT], es);
        unsigned* lu = (unsigned*)(wsF + WS_LOAD);
        #pragma unroll
        for (int e = 0; e < E_; ++e)
            if (loadL[e]) atomicAdd(&lu[e], loadL[e]);
    }
}

__global__ void finalize_kernel(const float* __restrict__ wsF,
                                float* __restrict__ out)
{
    if (threadIdx.x == 0 && blockIdx.x == 0) {
        const unsigned* lu = (const unsigned*)(wsF + WS_LOAD);
        double m = 0.0, l[E_];
        #pragma unroll
        for (int e = 0; e < E_; ++e) { l[e] = (double)lu[e]; m += l[e]; }
        m /= (double)E_;
        double var = 0.0;
        #pragma unroll
        for (int e = 0; e < E_; ++e) { double d = l[e] - m; var += d * d; }
        var /= (double)(E_ - 1);
        double stdl = sqrt(var);
        // std(importance) == 0 exactly (top-2 always picks 2 of 6)
        double ent = (double)wsF[WS_ENT] / (double)NTOK;
        out[(size_t)NTOK * E_ + (size_t)NTOK * 2] = (float)(0.1 * ent + 0.2 * stdl);
    }
}

extern "C" void kernel_launch(void* const* d_in, const int* in_sizes, int n_in,
                              void* d_out, int out_size, void* d_ws, size_t ws_size,
                              hipStream_t stream)
{
    const float* x            = (const float*)d_in[0];
    const float* noise        = (const float*)d_in[1];
    const int*   expert_types = (const int*)  d_in[2];
    const float* type_emb     = (const float*)d_in[3];
    const float* nw1          = (const float*)d_in[4];
    const float* nb1          = (const float*)d_in[5];
    const float* nw2          = (const float*)d_in[6];
    const float* nb2          = (const float*)d_in[7];
    const float* rw1          = (const float*)d_in[8];
    const float* rb1          = (const float*)d_in[9];
    const float* rw2          = (const float*)d_in[10];
    const float* rb2          = (const float*)d_in[11];
    const float* temperature  = (const float*)d_in[12];
    float* out = (float*)d_out;
    float* wsF = (float*)d_ws;

    prep_kernel<<<NNT + 10, 256, 0, stream>>>(type_emb, rw1, rb1, rw2, rb2,
                                              temperature, nw1, wsF);
    router_mfma<<<NBLK, 256, 0, stream>>>(x, noise, expert_types,
                                          nb1, nw2, nb2, wsF, out);
    finalize_kernel<<<1, 64, 0, stream>>>(wsF, out);
}